// Round 19
// baseline (383.078 us; speedup 1.0000x reference)
//
#include <hip/hip_runtime.h>
#include <math.h>

#define BB 8
#define NN 2048
#define FIN 128
#define FOUT 64
#define TI 16
#define TJ 256
#define TJP (TJ + 8)
#define NTILE (NN / TJ)
#define PREP 4            // probe internal repeat (lifts probes above 78us fills)

typedef short bf16x8 __attribute__((ext_vector_type(8)));
typedef float f32x4 __attribute__((ext_vector_type(4)));

__device__ __forceinline__ float exp_tanh(float z) {
    float zc = fminf(fmaxf(z, -15.f), 15.f);
    float u = __expf(zc + zc);
    float tn = (u - 1.f) * __builtin_amdgcn_rcpf(u + 1.f);
    return __expf(tn);
}

__device__ __forceinline__ unsigned short f2bf(float x) {
    union { float f; unsigned u; } v; v.f = x;
    unsigned r = v.u + 0x7FFF + ((v.u >> 16) & 1);
    return (unsigned short)(r >> 16);
}

// K1: verbatim R20 (panel-major ht[b][n/32][c][n%32])
__global__ __launch_bounds__(256, 2) void gat_k1(const float* __restrict__ x,
                                                 const float* __restrict__ W,
                                                 const float* __restrict__ a,
                                                 unsigned short* __restrict__ ht,
                                                 float* __restrict__ f1,
                                                 float* __restrict__ f2) {
    __shared__ __attribute__((aligned(16))) float Wl[FIN][FOUT];
    __shared__ __attribute__((aligned(16))) float xs[16][FIN];
    int t = threadIdx.x;

    const float4* W4 = (const float4*)W;
    float4* Wl4 = (float4*)&Wl[0][0];
#pragma unroll
    for (int kk = 0; kk < 8; ++kk) Wl4[t + 256 * kk] = W4[t + 256 * kk];

    size_t row0 = (size_t)blockIdx.x * 16;
    const float4* x4 = (const float4*)(x + row0 * FIN);
    float4* xs4 = (float4*)&xs[0][0];
#pragma unroll
    for (int kk = 0; kk < 2; ++kk) xs4[t + 256 * kk] = x4[t + 256 * kk];
    __syncthreads();

    int c = t & 63;
    int rq = t >> 6;
    float acc[4] = {0.f, 0.f, 0.f, 0.f};
#pragma unroll 8
    for (int k = 0; k < FIN; ++k) {
        float wv = Wl[k][c];
        acc[0] = fmaf(xs[rq][k], wv, acc[0]);
        acc[1] = fmaf(xs[rq + 4][k], wv, acc[1]);
        acc[2] = fmaf(xs[rq + 8][k], wv, acc[2]);
        acc[3] = fmaf(xs[rq + 12][k], wv, acc[3]);
    }
    float a1c = a[c], a2c = a[FOUT + c];
#pragma unroll
    for (int m = 0; m < 4; ++m) {
        size_t bn = row0 + rq + 4 * m;
        int b = (int)(bn >> 11);
        int n = (int)(bn & 2047);
        ht[((size_t)b * (NN / 32) + (n >> 5)) * (FOUT * 32) + c * 32 + (n & 31)] =
            f2bf(acc[m]);
        float p1 = acc[m] * a1c;
        float p2 = acc[m] * a2c;
#pragma unroll
        for (int off = 32; off > 0; off >>= 1) {
            p1 += __shfl_down(p1, off, 64);
            p2 += __shfl_down(p2, off, 64);
        }
        if (c == 0) { f1[bn] = p1; f2[bn] = p2; }
    }
}

// K2f: byte-identical to R20 (216.3us best). Writes out.
__global__ __launch_bounds__(256) void gat_k2f(const int* __restrict__ adj,
                                               const unsigned short* __restrict__ ht,
                                               const float* __restrict__ f1,
                                               const float* __restrict__ f2,
                                               float* __restrict__ out) {
    __shared__ __attribute__((aligned(16))) unsigned short pb[TI][TJP];
    __shared__ __attribute__((aligned(16))) float f2s[TJ];
    __shared__ float f1s[TI];
    __shared__ float rsw[TI];

    int t = threadIdx.x;
    int i0 = blockIdx.x * TI;
    int b = blockIdx.y;

    int lane = t & 63;
    int w = t >> 6;
    int mrow = lane & 15;
    int quad = lane >> 4;
    int j4 = t & 63;

    if (t < TI) f1s[t] = f1[(size_t)b * NN + i0 + t];
    __syncthreads();

    float f1r[4];
    float ps[4];
#pragma unroll
    for (int m = 0; m < 4; ++m) {
        f1r[m] = f1s[w + 4 * m];
        ps[m] = 0.f;
    }
    f32x4 acc = {0.f, 0.f, 0.f, 0.f};

    const int* adjrow = adj + (((size_t)b * NN + i0) * NN) + 4 * j4;
    const unsigned short* htb =
        ht + (size_t)b * (NN / 32) * (FOUT * 32)
           + (size_t)(w * 16 + mrow) * 32 + 8 * quad;

    for (int jt = 0; jt < NTILE; ++jt) {
        int j0 = jt * TJ;

        int4 avreg[4];
#pragma unroll
        for (int m = 0; m < 4; ++m)
            avreg[m] = *(const int4*)(adjrow + (size_t)(w + 4 * m) * NN + j0);

        f2s[t] = f2[(size_t)b * NN + j0 + t];
        __syncthreads();

        float4 fv = ((const float4*)f2s)[j4];
#pragma unroll
        for (int m = 0; m < 4; ++m) {
            int4 av = avreg[m];
            float f1i = f1r[m];
            float4 p;
            p.x = (av.x > 0) ? exp_tanh(f1i + fv.x) : 0.f;
            p.y = (av.y > 0) ? exp_tanh(f1i + fv.y) : 0.f;
            p.z = (av.z > 0) ? exp_tanh(f1i + fv.z) : 0.f;
            p.w = (av.w > 0) ? exp_tanh(f1i + fv.w) : 0.f;
            ps[m] += p.x + p.y + p.z + p.w;
            ushort4 pk;
            pk.x = f2bf(p.x); pk.y = f2bf(p.y);
            pk.z = f2bf(p.z); pk.w = f2bf(p.w);
            *(ushort4*)&pb[w + 4 * m][4 * j4] = pk;
        }
        __syncthreads();

        const unsigned short* prow = &pb[mrow][8 * quad];
        const unsigned short* hpan = htb + (size_t)(j0 >> 5) * (FOUT * 32);
#pragma unroll
        for (int ch = 0; ch < TJ / 32; ++ch) {
            bf16x8 af = *(const bf16x8*)(prow + 32 * ch);
            bf16x8 bf = *(const bf16x8*)(hpan + (size_t)ch * (FOUT * 32));
            acc = __builtin_amdgcn_mfma_f32_16x16x32_bf16(af, bf, acc, 0, 0, 0);
        }
    }

#pragma unroll
    for (int m = 0; m < 4; ++m) {
        float s = ps[m];
#pragma unroll
        for (int off = 32; off > 0; off >>= 1) s += __shfl_down(s, off, 64);
        if (lane == 0) rsw[w + 4 * m] = s;
    }
    __syncthreads();

    float* op = out + ((size_t)b * NN + i0) * FOUT + w * 16 + mrow;
#pragma unroll
    for (int u = 0; u < 4; ++u) {
        int row = quad * 4 + u;
        float rinv = __builtin_amdgcn_rcpf(rsw[row]);
        float sx = acc[u] * rinv;
        op[(size_t)row * FOUT] = (sx > 0.f) ? sx : expm1f(sx);
    }
}

// P1 "skeleton" probe (R21): adj loads + f2s stage + both barriers, x4 reps.
// exp/LDS-write/MFMA skipped; loads kept live via data-dependent sink.
// Rep-permuted tile order makes addresses rep-dependent (defeats CSE).
__global__ __launch_bounds__(256) void gat_p1(const int* __restrict__ adj,
                                              const float* __restrict__ f2,
                                              float* __restrict__ scr) {
    __shared__ __attribute__((aligned(16))) float f2s[TJ];
    int t = threadIdx.x;
    int i0 = blockIdx.x * TI;
    int b = blockIdx.y;
    int w = t >> 6;
    int j4 = t & 63;

    const int* adjrow = adj + (((size_t)b * NN + i0) * NN) + 4 * j4;
    float sink = 0.f;

#pragma unroll 1
    for (int rep = 0; rep < PREP; ++rep) {
#pragma unroll 1
        for (int jt = 0; jt < NTILE; ++jt) {
            int j0 = (((jt + rep) & (NTILE - 1))) * TJ;

            int4 avreg[4];
#pragma unroll
            for (int m = 0; m < 4; ++m)
                avreg[m] = *(const int4*)(adjrow + (size_t)(w + 4 * m) * NN + j0);

            f2s[t] = f2[(size_t)b * NN + j0 + t];
            __syncthreads();

            float4 fv = ((const float4*)f2s)[j4];
            sink += fv.x + fv.y + fv.z + fv.w;
#pragma unroll
            for (int m = 0; m < 4; ++m)
                sink += (float)(avreg[m].x + avreg[m].y + avreg[m].z + avreg[m].w);
            __syncthreads();
        }
    }
    scr[((size_t)b * (NN / TI) + blockIdx.x) * 256 + t] = sink;
}

// P2 "skeleton + p-phase" probe (R21): P1 + full exp_tanh/pack/LDS-write,
// + 1-elem LDS read-back per tile (keeps pb stores meaningful). No MFMA/ht.
__global__ __launch_bounds__(256) void gat_p2(const int* __restrict__ adj,
                                              const float* __restrict__ f1,
                                              const float* __restrict__ f2,
                                              float* __restrict__ scr) {
    __shared__ __attribute__((aligned(16))) unsigned short pb[TI][TJP];
    __shared__ __attribute__((aligned(16))) float f2s[TJ];
    __shared__ float f1s[TI];
    int t = threadIdx.x;
    int i0 = blockIdx.x * TI;
    int b = blockIdx.y;
    int w = t >> 6;
    int j4 = t & 63;

    if (t < TI) f1s[t] = f1[(size_t)b * NN + i0 + t];
    __syncthreads();
    float f1r[4];
    float ps[4];
#pragma unroll
    for (int m = 0; m < 4; ++m) {
        f1r[m] = f1s[w + 4 * m];
        ps[m] = 0.f;
    }

    const int* adjrow = adj + (((size_t)b * NN + i0) * NN) + 4 * j4;
    float sink = 0.f;

#pragma unroll 1
    for (int rep = 0; rep < PREP; ++rep) {
#pragma unroll 1
        for (int jt = 0; jt < NTILE; ++jt) {
            int j0 = (((jt + rep) & (NTILE - 1))) * TJ;

            int4 avreg[4];
#pragma unroll
            for (int m = 0; m < 4; ++m)
                avreg[m] = *(const int4*)(adjrow + (size_t)(w + 4 * m) * NN + j0);

            f2s[t] = f2[(size_t)b * NN + j0 + t];
            __syncthreads();

            float4 fv = ((const float4*)f2s)[j4];
#pragma unroll
            for (int m = 0; m < 4; ++m) {
                int4 av = avreg[m];
                float f1i = f1r[m];
                float4 p;
                p.x = (av.x > 0) ? exp_tanh(f1i + fv.x) : 0.f;
                p.y = (av.y > 0) ? exp_tanh(f1i + fv.y) : 0.f;
                p.z = (av.z > 0) ? exp_tanh(f1i + fv.z) : 0.f;
                p.w = (av.w > 0) ? exp_tanh(f1i + fv.w) : 0.f;
                ps[m] += p.x + p.y + p.z + p.w;
                ushort4 pk;
                pk.x = f2bf(p.x); pk.y = f2bf(p.y);
                pk.z = f2bf(p.z); pk.w = f2bf(p.w);
                *(ushort4*)&pb[w + 4 * m][4 * j4] = pk;
            }
            __syncthreads();

            // minimal consume of pb so stores stay meaningful
            sink += (float)pb[t >> 4][(t & 15) * 16];
        }
    }
#pragma unroll
    for (int m = 0; m < 4; ++m) sink += ps[m];
    scr[((size_t)b * (NN / TI) + blockIdx.x) * 256 + t] = sink;
}

extern "C" void kernel_launch(void* const* d_in, const int* in_sizes, int n_in,
                              void* d_out, int out_size, void* d_ws, size_t ws_size,
                              hipStream_t stream) {
    const float* x   = (const float*)d_in[0];
    const int*   adj = (const int*)d_in[1];
    const float* W   = (const float*)d_in[2];
    const float* a   = (const float*)d_in[3];
    float* out = (float*)d_out;

    unsigned short* ht = (unsigned short*)d_ws;          // 2.1 MB
    float* f1   = (float*)(ht + (size_t)BB * FOUT * NN); // B*N
    float* f2   = f1 + (size_t)BB * NN;                  // B*N
    float* scr1 = f2 + (size_t)BB * NN;                  // 1 MB probe sink
    float* scr2 = scr1 + (size_t)BB * (NN / TI) * 256;   // 1 MB probe sink

    gat_k1<<<dim3(BB * NN / 16), dim3(256), 0, stream>>>(x, W, a, ht, f1, f2);
    gat_k2f<<<dim3(NN / TI, BB), dim3(256), 0, stream>>>(adj, ht, f1, f2, out);
    // R21 instrumentation (out already written; probes touch only ws scratch)
    gat_p1<<<dim3(NN / TI, BB), dim3(256), 0, stream>>>(adj, f2, scr1);
    gat_p2<<<dim3(NN / TI, BB), dim3(256), 0, stream>>>(adj, f1, f2, scr2);
}

// Round 21
// 217.330 us; speedup vs baseline: 1.7627x; 1.7627x over previous
//
#include <hip/hip_runtime.h>
#include <math.h>

#define BB 8
#define NN 2048
#define FIN 128
#define FOUT 64
#define TI 16
#define TJ 256
#define TJP (TJ + 8)
#define NTILE (NN / TJ)

typedef short bf16x8 __attribute__((ext_vector_type(8)));
typedef float f32x4 __attribute__((ext_vector_type(4)));

__device__ __forceinline__ float exp_tanh(float z) {
    float zc = fminf(fmaxf(z, -15.f), 15.f);
    float u = __expf(zc + zc);
    float tn = (u - 1.f) * __builtin_amdgcn_rcpf(u + 1.f);
    return __expf(tn);
}

__device__ __forceinline__ unsigned short f2bf(float x) {
    union { float f; unsigned u; } v; v.f = x;
    unsigned r = v.u + 0x7FFF + ((v.u >> 16) & 1);
    return (unsigned short)(r >> 16);
}

// K1: verbatim R20 (panel-major ht[b][n/32][c][n%32])
__global__ __launch_bounds__(256, 2) void gat_k1(const float* __restrict__ x,
                                                 const float* __restrict__ W,
                                                 const float* __restrict__ a,
                                                 unsigned short* __restrict__ ht,
                                                 float* __restrict__ f1,
                                                 float* __restrict__ f2) {
    __shared__ __attribute__((aligned(16))) float Wl[FIN][FOUT];
    __shared__ __attribute__((aligned(16))) float xs[16][FIN];
    int t = threadIdx.x;

    const float4* W4 = (const float4*)W;
    float4* Wl4 = (float4*)&Wl[0][0];
#pragma unroll
    for (int kk = 0; kk < 8; ++kk) Wl4[t + 256 * kk] = W4[t + 256 * kk];

    size_t row0 = (size_t)blockIdx.x * 16;
    const float4* x4 = (const float4*)(x + row0 * FIN);
    float4* xs4 = (float4*)&xs[0][0];
#pragma unroll
    for (int kk = 0; kk < 2; ++kk) xs4[t + 256 * kk] = x4[t + 256 * kk];
    __syncthreads();

    int c = t & 63;
    int rq = t >> 6;
    float acc[4] = {0.f, 0.f, 0.f, 0.f};
#pragma unroll 8
    for (int k = 0; k < FIN; ++k) {
        float wv = Wl[k][c];
        acc[0] = fmaf(xs[rq][k], wv, acc[0]);
        acc[1] = fmaf(xs[rq + 4][k], wv, acc[1]);
        acc[2] = fmaf(xs[rq + 8][k], wv, acc[2]);
        acc[3] = fmaf(xs[rq + 12][k], wv, acc[3]);
    }
    float a1c = a[c], a2c = a[FOUT + c];
#pragma unroll
    for (int m = 0; m < 4; ++m) {
        size_t bn = row0 + rq + 4 * m;
        int b = (int)(bn >> 11);
        int n = (int)(bn & 2047);
        ht[((size_t)b * (NN / 32) + (n >> 5)) * (FOUT * 32) + c * 32 + (n & 31)] =
            f2bf(acc[m]);
        float p1 = acc[m] * a1c;
        float p2 = acc[m] * a2c;
#pragma unroll
        for (int off = 32; off > 0; off >>= 1) {
            p1 += __shfl_down(p1, off, 64);
            p2 += __shfl_down(p2, off, 64);
        }
        if (c == 0) { f1[bn] = p1; f2[bn] = p2; }
    }
}

// K2f R22: R20 structure + B-FRAGMENT BATCH HOIST.
// R21 ablation (P1/P2 probes): skeleton = 18-25us (at L3 BW ceiling,
// efficient), p-phase = +5us (VALU 75%), PV+epilogue = ~80-85us = THE
// GHOST, with only ~2us of MFMA in it. Mechanism: at 48 VGPR the
// compiler can't keep 8 B-frags (32 VGPR) in flight -> PV serializes
// load-bf/wait/MFMA x8 per tile per wave at L2 latency, and the
// lockstep barriers make all waves stall together. Fix: load ALL 8
// B-frags into registers at the tile top with the adj loads (batched
// issue, one drain at the first barrier -- the R16 adj pattern), so PV
// is pure LDS-af + MFMA. sched_barrier(0) stops the scheduler from
// sinking the loads back into PV. Est ~96 VGPR -> same 4 waves/SIMD.
__global__ __launch_bounds__(256) void gat_k2f(const int* __restrict__ adj,
                                               const unsigned short* __restrict__ ht,
                                               const float* __restrict__ f1,
                                               const float* __restrict__ f2,
                                               float* __restrict__ out) {
    __shared__ __attribute__((aligned(16))) unsigned short pb[TI][TJP];
    __shared__ __attribute__((aligned(16))) float f2s[TJ];
    __shared__ float f1s[TI];
    __shared__ float rsw[TI];

    int t = threadIdx.x;
    int i0 = blockIdx.x * TI;
    int b = blockIdx.y;

    int lane = t & 63;
    int w = t >> 6;
    int mrow = lane & 15;
    int quad = lane >> 4;
    int j4 = t & 63;

    if (t < TI) f1s[t] = f1[(size_t)b * NN + i0 + t];
    __syncthreads();

    float f1r[4];
    float ps[4];
#pragma unroll
    for (int m = 0; m < 4; ++m) {
        f1r[m] = f1s[w + 4 * m];
        ps[m] = 0.f;
    }
    f32x4 acc = {0.f, 0.f, 0.f, 0.f};

    const int* adjrow = adj + (((size_t)b * NN + i0) * NN) + 4 * j4;
    const unsigned short* htb =
        ht + (size_t)b * (NN / 32) * (FOUT * 32)
           + (size_t)(w * 16 + mrow) * 32 + 8 * quad;

    for (int jt = 0; jt < NTILE; ++jt) {
        int j0 = jt * TJ;

        // ---- tile-top load batch: adj + ALL 8 B-frags issue together ----
        int4 avreg[4];
#pragma unroll
        for (int m = 0; m < 4; ++m)
            avreg[m] = *(const int4*)(adjrow + (size_t)(w + 4 * m) * NN + j0);

        const unsigned short* hpan = htb + (size_t)(j0 >> 5) * (FOUT * 32);
        bf16x8 bfreg[8];
#pragma unroll
        for (int ch = 0; ch < TJ / 32; ++ch)
            bfreg[ch] = *(const bf16x8*)(hpan + (size_t)ch * (FOUT * 32));

        // keep the batch issued here; don't let the scheduler sink it into PV
        __builtin_amdgcn_sched_barrier(0);

        f2s[t] = f2[(size_t)b * NN + j0 + t];
        __syncthreads();   // single vmcnt(0) drain covers the whole batch

        // ---- p-phase: mask -> exp(tanh) -> bf16 into LDS ----
        float4 fv = ((const float4*)f2s)[j4];
#pragma unroll
        for (int m = 0; m < 4; ++m) {
            int4 av = avreg[m];
            float f1i = f1r[m];
            float4 p;
            p.x = (av.x > 0) ? exp_tanh(f1i + fv.x) : 0.f;
            p.y = (av.y > 0) ? exp_tanh(f1i + fv.y) : 0.f;
            p.z = (av.z > 0) ? exp_tanh(f1i + fv.z) : 0.f;
            p.w = (av.w > 0) ? exp_tanh(f1i + fv.w) : 0.f;
            ps[m] += p.x + p.y + p.z + p.w;
            ushort4 pk;
            pk.x = f2bf(p.x); pk.y = f2bf(p.y);
            pk.z = f2bf(p.z); pk.w = f2bf(p.w);
            *(ushort4*)&pb[w + 4 * m][4 * j4] = pk;
        }
        __syncthreads();

        // ---- PV: pure LDS-af + MFMA (zero global loads) ----
        const unsigned short* prow = &pb[mrow][8 * quad];
#pragma unroll
        for (int ch = 0; ch < TJ / 32; ++ch) {
            bf16x8 af = *(const bf16x8*)(prow + 32 * ch);
            acc = __builtin_amdgcn_mfma_f32_16x16x32_bf16(af, bfreg[ch], acc, 0, 0, 0);
        }
    }

#pragma unroll
    for (int m = 0; m < 4; ++m) {
        float s = ps[m];
#pragma unroll
        for (int off = 32; off > 0; off >>= 1) s += __shfl_down(s, off, 64);
        if (lane == 0) rsw[w + 4 * m] = s;
    }
    __syncthreads();

    float* op = out + ((size_t)b * NN + i0) * FOUT + w * 16 + mrow;
#pragma unroll
    for (int u = 0; u < 4; ++u) {
        int row = quad * 4 + u;
        float rinv = __builtin_amdgcn_rcpf(rsw[row]);
        float sx = acc[u] * rinv;
        op[(size_t)row * FOUT] = (sx > 0.f) ? sx : expm1f(sx);
    }
}

extern "C" void kernel_launch(void* const* d_in, const int* in_sizes, int n_in,
                              void* d_out, int out_size, void* d_ws, size_t ws_size,
                              hipStream_t stream) {
    const float* x   = (const float*)d_in[0];
    const int*   adj = (const int*)d_in[1];
    const float* W   = (const float*)d_in[2];
    const float* a   = (const float*)d_in[3];
    float* out = (float*)d_out;

    unsigned short* ht = (unsigned short*)d_ws;          // 2.1 MB, panel-major
    float* f1   = (float*)(ht + (size_t)BB * FOUT * NN); // B*N
    float* f2   = f1 + (size_t)BB * NN;                  // B*N

    gat_k1<<<dim3(BB * NN / 16), dim3(256), 0, stream>>>(x, W, a, ht, f1, f2);
    gat_k2f<<<dim3(NN / TI, BB), dim3(256), 0, stream>>>(adj, ht, f1, f2, out);
}